// Round 4
// baseline (5340.911 us; speedup 1.0000x reference)
//
#include <hip/hip_runtime.h>

// LightGCN on MI355X (gfx950). Round 4.
// R3 evidence: scatter ~380us at WRITE_SIZE 297MB = 64B/edge -> random 8B writes
// dirty a full line each (write-back thrash), NOT write-BW bound; spmm ~200us/layer
// is gather-LATENCY bound (1 row/wave, 4 gathers in flight, deg~32).
// Changes: (1) coarse bucket partition (128 rows/bucket, K=1172) via radix-partition
// pattern: per-block LDS hist -> reserve runs -> contiguous run writes (time-clustered,
// ~112B/run); (2) SpMM = one block per bucket, LDS fp32 accumulator + ds_add_f32,
// every edge independent (unroll 8, ~20 waves/CU -> ~160 gathers in flight/CU);
// (3) layer-3 writeback fuses the stage-mean (kills final kernel + y3 buffer).

#define NUSERS 100000
#define NITEMS 50000
#define NTOT   150000
#define DIM    64
#define NNZ_E  4800000

#define RB      128                              // rows per bucket
#define BSHIFT  7
#define NBUCK   ((NTOT + RB - 1) / RB)           // 1172
#define CHUNK_E 16384
#define NPART   ((NNZ_E + CHUNK_E - 1) / CHUNK_E) // 293
#define UNROLL  8

constexpr int TOT4 = NTOT * DIM / 4;    // 2,400,000
constexpr int USR4 = NUSERS * DIM / 4;  // 1,600,000

__device__ __forceinline__ float bdec(unsigned short u) {
    union { unsigned u32; float f; } t; t.u32 = (unsigned)u << 16; return t.f;
}
__device__ __forceinline__ unsigned short benc(float f) {
    union { float f; unsigned u; } t; t.f = f;
    unsigned r = t.u + 0x7FFFu + ((t.u >> 16) & 1u);   // RNE
    return (unsigned short)(r >> 16);
}

__global__ void zero_int(int* __restrict__ p, int n) {
    int i = blockIdx.x * blockDim.x + threadIdx.x;
    if (i < n) p[i] = 0;
}

// Bucket histogram, LDS-aggregated: 4.8M LDS atomics + ~512*1172 global atomics.
__global__ void hist_kernel(const int* __restrict__ rows, int* __restrict__ cnt) {
    __shared__ int l[NBUCK];
    for (int k = threadIdx.x; k < NBUCK; k += blockDim.x) l[k] = 0;
    __syncthreads();
    int stride = gridDim.x * blockDim.x;
    for (int e = blockIdx.x * blockDim.x + threadIdx.x; e < NNZ_E; e += stride)
        atomicAdd(&l[rows[e] >> BSHIFT], 1);
    __syncthreads();
    for (int k = threadIdx.x; k < NBUCK; k += blockDim.x)
        if (l[k]) atomicAdd(&cnt[k], l[k]);
}

// Exclusive scan over cnt[NBUCK] -> bptr[NBUCK+1] and gcur (mutable copy).
__global__ void scan_kernel(const int* __restrict__ cnt, int* __restrict__ bptr,
                            int* __restrict__ gcur) {
    __shared__ int tmp[1024];
    int tid = threadIdx.x;
    int i0 = tid * 2;
    int a = (i0     < NBUCK) ? cnt[i0]     : 0;
    int b = (i0 + 1 < NBUCK) ? cnt[i0 + 1] : 0;
    int s = a + b;
    tmp[tid] = s;
    __syncthreads();
    for (int ofs = 1; ofs < 1024; ofs <<= 1) {
        int v = (tid >= ofs) ? tmp[tid - ofs] : 0;
        __syncthreads();
        tmp[tid] += v;
        __syncthreads();
    }
    int excl = tmp[tid] - s;
    if (i0 < NBUCK)     { bptr[i0] = excl;         gcur[i0] = excl; }
    if (i0 + 1 < NBUCK) { bptr[i0 + 1] = excl + a; gcur[i0 + 1] = excl + a; }
    if (tid == 1023) bptr[NBUCK] = tmp[tid];
}

// Radix-partition style binning: per-block LDS hist -> reserve contiguous runs ->
// write each (block,bucket) run contiguously. Edge word: col | row_local<<20.
__global__ void partition_kernel(const int* __restrict__ rows, const int* __restrict__ cols,
                                 const float* __restrict__ vals,
                                 int* __restrict__ gcur, int2* __restrict__ edges) {
    __shared__ int l[NBUCK];
    int c0 = blockIdx.x * CHUNK_E;
    int c1 = c0 + CHUNK_E; if (c1 > NNZ_E) c1 = NNZ_E;
    for (int k = threadIdx.x; k < NBUCK; k += blockDim.x) l[k] = 0;
    __syncthreads();
    for (int e = c0 + threadIdx.x; e < c1; e += blockDim.x)
        atomicAdd(&l[rows[e] >> BSHIFT], 1);
    __syncthreads();
    for (int k = threadIdx.x; k < NBUCK; k += blockDim.x) {
        int c = l[k];
        l[k] = c ? atomicAdd(&gcur[k], c) : 0;   // l[k] becomes this block's run cursor
    }
    __syncthreads();
    for (int e = c0 + threadIdx.x; e < c1; e += blockDim.x) {
        int r = rows[e];
        int b = r >> BSHIFT, rl = r & (RB - 1);
        int p = atomicAdd(&l[b], 1);
        edges[p] = make_int2(cols[e] | (rl << 20), __float_as_int(vals[e]));
    }
}

// x0h = bf16(concat(user, item))
__global__ void convert_kernel(const float* __restrict__ user, const float* __restrict__ item,
                               ushort4* __restrict__ xh) {
    int i = blockIdx.x * blockDim.x + threadIdx.x;
    if (i >= TOT4) return;
    float4 v = (i < USR4) ? ((const float4*)user)[i]
                          : ((const float4*)item)[i - USR4];
    ushort4 o;
    o.x = benc(v.x); o.y = benc(v.y); o.z = benc(v.z); o.w = benc(v.w);
    xh[i] = o;
}

// One block per bucket. LDS fp32 accumulator (128 rows x 64). Edges independent:
// gather bf16 row slice + ds_add_f32. last=1 fuses the stage-mean writeback.
__global__ void __launch_bounds__(256)
spmm_kernel(const int* __restrict__ bptr, const int2* __restrict__ edges,
            const unsigned short* __restrict__ xh, unsigned short* __restrict__ yh,
            const float* __restrict__ user, const float* __restrict__ item,
            const unsigned short* __restrict__ y1h, const unsigned short* __restrict__ y2h,
            float* __restrict__ out, int last) {
    __shared__ float acc[RB * DIM];   // 32 KB
    int b = blockIdx.x;
    for (int t = threadIdx.x; t < RB * DIM; t += blockDim.x) acc[t] = 0.f;
    __syncthreads();

    int lane = threadIdx.x & 63;
    int w = __builtin_amdgcn_readfirstlane(threadIdx.x >> 6);   // 0..3
    int start = __builtin_amdgcn_readfirstlane(bptr[b]);
    int end   = __builtin_amdgcn_readfirstlane(bptr[b + 1]);

    int i = start + w * UNROLL;
    for (; i + UNROLL <= end; i += 4 * UNROLL) {
        int2 e[UNROLL];
#pragma unroll
        for (int u = 0; u < UNROLL; ++u) e[u] = edges[i + u];
        float xv[UNROLL];
#pragma unroll
        for (int u = 0; u < UNROLL; ++u)
            xv[u] = bdec(xh[(size_t)(e[u].x & 0xFFFFF) * DIM + lane]);
#pragma unroll
        for (int u = 0; u < UNROLL; ++u)
            atomicAdd(&acc[(e[u].x >> 20) * DIM + lane],
                      __int_as_float(e[u].y) * xv[u]);
    }
    // exactly one wave has a non-empty tail (see stride analysis)
    for (; i < end; ++i) {
        int2 e = edges[i];
        atomicAdd(&acc[(e.x >> 20) * DIM + lane],
                  __int_as_float(e.y) * bdec(xh[(size_t)(e.x & 0xFFFFF) * DIM + lane]));
    }
    __syncthreads();

    int base = b * RB;
    if (!last) {
        for (int t = threadIdx.x; t < RB * DIM; t += blockDim.x) {
            int r = base + (t >> 6);
            if (r < NTOT) yh[(size_t)r * DIM + (t & 63)] = benc(acc[t]);
        }
    } else {
        for (int t = threadIdx.x; t < RB * DIM; t += blockDim.x) {
            int r = base + (t >> 6);
            if (r < NTOT) {
                int d = t & 63;
                size_t o = (size_t)r * DIM + d;
                float x0 = (r < NUSERS) ? user[o] : item[o - (size_t)NUSERS * DIM];
                out[o] = 0.25f * (x0 + bdec(y1h[o]) + bdec(y2h[o]) + acc[t]);
            }
        }
    }
}

extern "C" void kernel_launch(void* const* d_in, const int* in_sizes, int n_in,
                              void* d_out, int out_size, void* d_ws, size_t ws_size,
                              hipStream_t stream) {
    const float* user = (const float*)d_in[0];
    const float* item = (const float*)d_in[1];
    const float* vals = (const float*)d_in[2];
    const int*   rows = (const int*)d_in[3];
    const int*   cols = (const int*)d_in[4];
    float* out = (float*)d_out;

    // ws layout (~96.2 MB): edges 38.4M | x0h 19.2M | y1h 19.2M | y2h 19.2M |
    // cnt 4.7K | bptr 4.7K | gcur 4.7K
    char* w = (char*)d_ws;
    int2*           edges = (int2*)w;           w += (size_t)NNZ_E * 8;
    unsigned short* x0h   = (unsigned short*)w; w += (size_t)NTOT * DIM * 2;
    unsigned short* y1h   = (unsigned short*)w; w += (size_t)NTOT * DIM * 2;
    unsigned short* y2h   = (unsigned short*)w; w += (size_t)NTOT * DIM * 2;
    int*            cnt   = (int*)w;            w += (size_t)NBUCK * 4;
    int*            bptr  = (int*)w;            w += (size_t)(NBUCK + 1) * 4;
    int*            gcur  = (int*)w;

    const int blk = 256;
    const int gElem = (TOT4 + blk - 1) / blk;   // 9375
    const int gCnt  = (NBUCK + blk - 1) / blk;  // 5

    // Bucket-partition build
    zero_int<<<gCnt, blk, 0, stream>>>(cnt, NBUCK);
    hist_kernel<<<512, blk, 0, stream>>>(rows, cnt);
    scan_kernel<<<1, 1024, 0, stream>>>(cnt, bptr, gcur);
    partition_kernel<<<NPART, 512, 0, stream>>>(rows, cols, vals, gcur, edges);

    // Layer input in bf16
    convert_kernel<<<gElem, blk, 0, stream>>>(user, item, (ushort4*)x0h);

    // 3 propagation layers; layer 3 fuses the stage-mean into out
    spmm_kernel<<<NBUCK, blk, 0, stream>>>(bptr, edges, x0h, y1h,
                                           user, item, y1h, y2h, out, 0);
    spmm_kernel<<<NBUCK, blk, 0, stream>>>(bptr, edges, y1h, y2h,
                                           user, item, y1h, y2h, out, 0);
    spmm_kernel<<<NBUCK, blk, 0, stream>>>(bptr, edges, y2h, y2h,
                                           user, item, y1h, y2h, out, 1);
}

// Round 5
// 593.351 us; speedup vs baseline: 9.0013x; 9.0013x over previous
//
#include <hip/hip_runtime.h>

// LightGCN on MI355X (gfx950). Round 5.
// R4 lesson: LDS fp32 atomic accumulation + low TLP = 8.5x regression (VALUBusy 2.5%,
// waves stalled on LDS RMW). Revert to R3's row-per-wave register-accum spmm.
// R3 lessons kept: scatter was write-thrash bound (297MB = 64B/edge); spmm was
// gather-latency bound (4 loads in flight).
// Changes: (1) two-phase counting sort: bucket partition (293 buckets x 512 rows,
// contiguous run writes) then per-bucket local sort with native LDS *int* atomics,
// write window ~130KB (L2-resident, lines fill before eviction). Emits rowptr free.
// (2) spmm: 2 rows/wave (half-wave ushort2 lanes) x unroll 8 = 16 gathers in flight.
// (3) layer-3 spmm fuses the stage-mean (no final kernel; 2 bf16 ping-pong buffers).

#define NUSERS 100000
#define NITEMS 50000
#define NTOT   150000
#define DIM    64
#define NNZ_E  4800000

#define RPB     512                               // rows per bucket
#define RSH     9
#define NBUCK   ((NTOT + RPB - 1) / RPB)          // 293
#define CHUNK_E 16384
#define NPART   ((NNZ_E + CHUNK_E - 1) / CHUNK_E) // 293

__device__ __forceinline__ unsigned short benc(float f) {
    union { float f; unsigned u; } t; t.f = f;
    unsigned r = t.u + 0x7FFFu + ((t.u >> 16) & 1u);   // RNE
    return (unsigned short)(r >> 16);
}
__device__ __forceinline__ float blo(unsigned g) { return __uint_as_float(g << 16); }
__device__ __forceinline__ float bhi(unsigned g) { return __uint_as_float(g & 0xFFFF0000u); }

__global__ void zero_int(int* __restrict__ p, int n) {
    int i = blockIdx.x * blockDim.x + threadIdx.x;
    if (i < n) p[i] = 0;
}

// Bucket histogram (293 counters), LDS-aggregated.
__global__ void histb_kernel(const int* __restrict__ rows, int* __restrict__ cnt) {
    __shared__ int l[NBUCK];
    for (int k = threadIdx.x; k < NBUCK; k += blockDim.x) l[k] = 0;
    __syncthreads();
    int stride = gridDim.x * blockDim.x;
    for (int e = blockIdx.x * blockDim.x + threadIdx.x; e < NNZ_E; e += stride)
        atomicAdd(&l[rows[e] >> RSH], 1);
    __syncthreads();
    for (int k = threadIdx.x; k < NBUCK; k += blockDim.x)
        if (l[k]) atomicAdd(&cnt[k], l[k]);
}

// Exclusive scan over cnt[NBUCK] -> bptr[NBUCK+1], gcur copy. One block, 512 thr.
__global__ void scanb_kernel(const int* __restrict__ cnt, int* __restrict__ bptr,
                             int* __restrict__ gcur) {
    __shared__ int t[512];
    int tid = threadIdx.x;
    int v = (tid < NBUCK) ? cnt[tid] : 0;
    t[tid] = v;
    __syncthreads();
    for (int ofs = 1; ofs < 512; ofs <<= 1) {
        int a = (tid >= ofs) ? t[tid - ofs] : 0;
        __syncthreads();
        t[tid] += a;
        __syncthreads();
    }
    int excl = t[tid] - v;
    if (tid < NBUCK) { bptr[tid] = excl; gcur[tid] = excl; }
    if (tid == 511) bptr[NBUCK] = t[511];
}

// Phase A: partition edges into buckets; contiguous run writes (~450B/run).
// tmp word: x = col | (row_local << 18)  (col<2^18=262144, rl<512), y = val bits.
__global__ void __launch_bounds__(512)
partA_kernel(const int* __restrict__ rows, const int* __restrict__ cols,
             const float* __restrict__ vals, int* __restrict__ gcur,
             int2* __restrict__ tmp) {
    __shared__ int l[NBUCK];
    int c0 = blockIdx.x * CHUNK_E;
    int c1 = c0 + CHUNK_E; if (c1 > NNZ_E) c1 = NNZ_E;
    for (int k = threadIdx.x; k < NBUCK; k += blockDim.x) l[k] = 0;
    __syncthreads();
    for (int e = c0 + threadIdx.x; e < c1; e += blockDim.x)
        atomicAdd(&l[rows[e] >> RSH], 1);
    __syncthreads();
    for (int k = threadIdx.x; k < NBUCK; k += blockDim.x) {
        int c = l[k];
        l[k] = c ? atomicAdd(&gcur[k], c) : 0;
    }
    __syncthreads();
    for (int e = c0 + threadIdx.x; e < c1; e += blockDim.x) {
        int r = rows[e];
        int b = r >> RSH, rl = r & (RPB - 1);
        int p = atomicAdd(&l[b], 1);
        tmp[p] = make_int2(cols[e] | (rl << 18), __float_as_int(vals[e]));
    }
}

// Phase B: per-bucket counting sort. Write window = bucket range (~130KB) ->
// L2-resident, no line thrash. Also emits rowptr. LDS *int* atomics only.
__global__ void __launch_bounds__(512)
partB_kernel(const int* __restrict__ bptr, const int2* __restrict__ tmp,
             int2* __restrict__ fin, int* __restrict__ rowptr) {
    __shared__ int cnt[RPB];
    __shared__ int cur[RPB];
    int b = blockIdx.x;
    int bb0 = bptr[b], bb1 = bptr[b + 1];
    int tid = threadIdx.x;
    cnt[tid] = 0;
    __syncthreads();
    for (int e = bb0 + tid; e < bb1; e += blockDim.x)
        atomicAdd(&cnt[((unsigned)tmp[e].x) >> 18], 1);
    __syncthreads();
    int v = cnt[tid];
    cur[tid] = v;
    __syncthreads();
    for (int ofs = 1; ofs < RPB; ofs <<= 1) {
        int a = (tid >= ofs) ? cur[tid - ofs] : 0;
        __syncthreads();
        cur[tid] += a;
        __syncthreads();
    }
    int excl = cur[tid] - v;
    int row = b * RPB + tid;
    if (row < NTOT) rowptr[row] = bb0 + excl;
    if (b == NBUCK - 1 && tid == 0) rowptr[NTOT] = bb1;
    __syncthreads();
    cur[tid] = excl;
    __syncthreads();
    for (int e = bb0 + tid; e < bb1; e += blockDim.x) {
        int2 t = tmp[e];
        int rl = ((unsigned)t.x) >> 18;
        int p = bb0 + atomicAdd(&cur[rl], 1);
        fin[p] = make_int2(t.x & 0x3FFFF, t.y);
    }
}

// x0h = bf16x2-packed concat(user, item). One uint per lane (2 components).
__global__ void convert_kernel(const float2* __restrict__ user, const float2* __restrict__ item,
                               unsigned* __restrict__ xh2) {
    int i = blockIdx.x * blockDim.x + threadIdx.x;   // uint index: row*32+sub
    if (i >= NTOT * 32) return;
    float2 v = (i < NUSERS * 32) ? user[i] : item[i - NUSERS * 32];
    xh2[i] = (unsigned)benc(v.x) | ((unsigned)benc(v.y) << 16);
}

// SpMM: 2 rows per wave (half-wave each, 32 ushort2 lanes = 128B row), unroll 8.
// Register accumulation, zero atomics. last=1 fuses out = 0.25*(x0+y1+y2+sum).
__global__ void __launch_bounds__(256)
spmm_kernel(const int* __restrict__ rowptr, const int2* __restrict__ ed,
            const unsigned* __restrict__ xin, unsigned* __restrict__ yout,
            const float2* __restrict__ user, const float2* __restrict__ item,
            const unsigned* __restrict__ y1, float2* __restrict__ out, int last) {
    int wid = blockIdx.x * (blockDim.x >> 6) + (threadIdx.x >> 6);
    int lane = threadIdx.x & 63;
    int half = lane >> 5, sub = lane & 31;
    int r = wid * 2 + half;
    if (r >= NTOT) return;
    int start = rowptr[r];
    int end   = rowptr[r + 1];
    float sx = 0.f, sy = 0.f;
    int i = start;
    for (; i + 8 <= end; i += 8) {
        int2 e[8];
#pragma unroll
        for (int u = 0; u < 8; ++u) e[u] = ed[i + u];
        unsigned g[8];
#pragma unroll
        for (int u = 0; u < 8; ++u) g[u] = xin[e[u].x * 32 + sub];
#pragma unroll
        for (int u = 0; u < 8; ++u) {
            float v = __int_as_float(e[u].y);
            sx += v * blo(g[u]);
            sy += v * bhi(g[u]);
        }
    }
    for (; i < end; ++i) {
        int2 e = ed[i];
        unsigned g = xin[e.x * 32 + sub];
        float v = __int_as_float(e.y);
        sx += v * blo(g);
        sy += v * bhi(g);
    }
    int o = r * 32 + sub;
    if (!last) {
        yout[o] = (unsigned)benc(sx) | ((unsigned)benc(sy) << 16);
    } else {
        float2 x0v = (r < NUSERS) ? user[o] : item[o - NUSERS * 32];
        unsigned u1 = y1[o];
        unsigned u2 = xin[o];   // layer-3 input IS y2
        float2 ov;
        ov.x = 0.25f * (x0v.x + blo(u1) + blo(u2) + sx);
        ov.y = 0.25f * (x0v.y + bhi(u1) + bhi(u2) + sy);
        out[o] = ov;
    }
}

extern "C" void kernel_launch(void* const* d_in, const int* in_sizes, int n_in,
                              void* d_out, int out_size, void* d_ws, size_t ws_size,
                              hipStream_t stream) {
    const float* user = (const float*)d_in[0];
    const float* item = (const float*)d_in[1];
    const float* vals = (const float*)d_in[2];
    const int*   rows = (const int*)d_in[3];
    const int*   cols = (const int*)d_in[4];
    float* out = (float*)d_out;

    // ws layout (~116.1 MB): tmp 38.4M | fin 38.4M | bufA 19.2M | bufB 19.2M |
    // rowptr 600K | cnt/bptr/gcur ~3.6K
    char* w = (char*)d_ws;
    int2*     tmp    = (int2*)w;     w += (size_t)NNZ_E * 8;
    int2*     fin    = (int2*)w;     w += (size_t)NNZ_E * 8;
    unsigned* bufA   = (unsigned*)w; w += (size_t)NTOT * DIM * 2;   // x0h, later y2h
    unsigned* bufB   = (unsigned*)w; w += (size_t)NTOT * DIM * 2;   // y1h
    int*      rowptr = (int*)w;      w += (size_t)(NTOT + 1) * 4;
    int*      cnt    = (int*)w;      w += (size_t)NBUCK * 4;
    int*      bptr   = (int*)w;      w += (size_t)(NBUCK + 1) * 4;
    int*      gcur   = (int*)w;

    const int blk = 256;
    const int gConv = (NTOT * 32 + blk - 1) / blk;   // 18750
    const int gSpmm = (NTOT / 2 + 3) / 4;            // 18750 (4 waves/block, 2 rows/wave)

    // Two-phase counting sort
    zero_int<<<2, blk, 0, stream>>>(cnt, NBUCK);
    histb_kernel<<<512, blk, 0, stream>>>(rows, cnt);
    scanb_kernel<<<1, 512, 0, stream>>>(cnt, bptr, gcur);
    partA_kernel<<<NPART, 512, 0, stream>>>(rows, cols, vals, gcur, tmp);
    partB_kernel<<<NBUCK, RPB, 0, stream>>>(bptr, tmp, fin, rowptr);

    // Layer input in bf16 (packed uint = 2 components/lane)
    convert_kernel<<<gConv, blk, 0, stream>>>((const float2*)user, (const float2*)item, bufA);

    // 3 propagation layers; layer 3 fuses the stage-mean into out
    spmm_kernel<<<gSpmm, blk, 0, stream>>>(rowptr, fin, bufA, bufB,
                                           (const float2*)user, (const float2*)item,
                                           bufB, (float2*)out, 0);   // y1 = bufB
    spmm_kernel<<<gSpmm, blk, 0, stream>>>(rowptr, fin, bufB, bufA,
                                           (const float2*)user, (const float2*)item,
                                           bufB, (float2*)out, 0);   // y2 = bufA
    spmm_kernel<<<gSpmm, blk, 0, stream>>>(rowptr, fin, bufA, bufA,
                                           (const float2*)user, (const float2*)item,
                                           bufB, (float2*)out, 1);   // fused mean
}

// Round 6
// 568.299 us; speedup vs baseline: 9.3981x; 1.0441x over previous
//
#include <hip/hip_runtime.h>

// LightGCN on MI355X (gfx950). Round 6.
// R5 evidence: spmm 104us/layer (VALUBusy 37%, latency-stall bound, 16 gathers in
// flight); partA 105us at 19% occupancy (only 9 waves/CU); partB ~75us.
// Changes: (1) spmm = 8 rows/wave, 8-lane octets, uint4 gathers (1KB/instr, 16B/lane),
// unroll 8 -> 64 edges in flight/wave, ~3 VALU/edge; (2) edges packed to 4B
// (col<<14 | val*16384, quant err 3e-5 << bf16 noise): edge stream halves;
// (3) partA chunk 8192 (586 blocks), partB 1024 threads, hist 1024 blocks.

#define NUSERS 100000
#define NITEMS 50000
#define NTOT   150000
#define DIM    64
#define NNZ_E  4800000

#define RPB     512                               // rows per bucket
#define RSH     9
#define NBUCK   ((NTOT + RPB - 1) / RPB)          // 293
#define CHUNK_E 8192
#define NPART   ((NNZ_E + CHUNK_E - 1) / CHUNK_E) // 586

__device__ __forceinline__ unsigned short benc(float f) {
    union { float f; unsigned u; } t; t.f = f;
    unsigned r = t.u + 0x7FFFu + ((t.u >> 16) & 1u);   // RNE
    return (unsigned short)(r >> 16);
}
__device__ __forceinline__ float blo(unsigned g) { return __uint_as_float(g << 16); }
__device__ __forceinline__ float bhi(unsigned g) { return __uint_as_float(g & 0xFFFF0000u); }

__global__ void zero_int(int* __restrict__ p, int n) {
    int i = blockIdx.x * blockDim.x + threadIdx.x;
    if (i < n) p[i] = 0;
}

// Bucket histogram (293 counters), LDS-aggregated, high TLP.
__global__ void histb_kernel(const int* __restrict__ rows, int* __restrict__ cnt) {
    __shared__ int l[NBUCK];
    for (int k = threadIdx.x; k < NBUCK; k += blockDim.x) l[k] = 0;
    __syncthreads();
    int stride = gridDim.x * blockDim.x;
    for (int e = blockIdx.x * blockDim.x + threadIdx.x; e < NNZ_E; e += stride)
        atomicAdd(&l[rows[e] >> RSH], 1);
    __syncthreads();
    for (int k = threadIdx.x; k < NBUCK; k += blockDim.x)
        if (l[k]) atomicAdd(&cnt[k], l[k]);
}

// Exclusive scan over cnt[NBUCK] -> bptr[NBUCK+1], gcur copy.
__global__ void scanb_kernel(const int* __restrict__ cnt, int* __restrict__ bptr,
                             int* __restrict__ gcur) {
    __shared__ int t[512];
    int tid = threadIdx.x;
    int v = (tid < NBUCK) ? cnt[tid] : 0;
    t[tid] = v;
    __syncthreads();
    for (int ofs = 1; ofs < 512; ofs <<= 1) {
        int a = (tid >= ofs) ? t[tid - ofs] : 0;
        __syncthreads();
        t[tid] += a;
        __syncthreads();
    }
    int excl = t[tid] - v;
    if (tid < NBUCK) { bptr[tid] = excl; gcur[tid] = excl; }
    if (tid == 511) bptr[NBUCK] = t[511];
}

// Phase A: partition edges into 293 buckets; contiguous run writes.
// tmp word: x = col | (row_local << 18), y = val fp32 bits.
__global__ void __launch_bounds__(512)
partA_kernel(const int* __restrict__ rows, const int* __restrict__ cols,
             const float* __restrict__ vals, int* __restrict__ gcur,
             int2* __restrict__ tmp) {
    __shared__ int l[NBUCK];
    int c0 = blockIdx.x * CHUNK_E;
    int c1 = c0 + CHUNK_E; if (c1 > NNZ_E) c1 = NNZ_E;
    for (int k = threadIdx.x; k < NBUCK; k += blockDim.x) l[k] = 0;
    __syncthreads();
    for (int e = c0 + threadIdx.x; e < c1; e += blockDim.x)
        atomicAdd(&l[rows[e] >> RSH], 1);
    __syncthreads();
    for (int k = threadIdx.x; k < NBUCK; k += blockDim.x) {
        int c = l[k];
        l[k] = c ? atomicAdd(&gcur[k], c) : 0;
    }
    __syncthreads();
    for (int e = c0 + threadIdx.x; e < c1; e += blockDim.x) {
        int r = rows[e];
        int b = r >> RSH, rl = r & (RPB - 1);
        int p = atomicAdd(&l[b], 1);
        tmp[p] = make_int2(cols[e] | (rl << 18), __float_as_int(vals[e]));
    }
}

// Phase B: per-bucket counting sort -> packed 4B edges + rowptr.
__global__ void __launch_bounds__(1024)
partB_kernel(const int* __restrict__ bptr, const int2* __restrict__ tmp,
             unsigned* __restrict__ fin, int* __restrict__ rowptr) {
    __shared__ int cnt[RPB];
    __shared__ int cur[RPB];
    int b = blockIdx.x;
    int bb0 = bptr[b], bb1 = bptr[b + 1];
    int tid = threadIdx.x;
    if (tid < RPB) cnt[tid] = 0;
    __syncthreads();
    for (int e = bb0 + tid; e < bb1; e += 1024)
        atomicAdd(&cnt[((unsigned)tmp[e].x) >> 18], 1);
    __syncthreads();
    int v = 0;
    if (tid < RPB) { v = cnt[tid]; cur[tid] = v; }
    __syncthreads();
    for (int ofs = 1; ofs < RPB; ofs <<= 1) {
        int a = (tid < RPB && tid >= ofs) ? cur[tid - ofs] : 0;
        __syncthreads();
        if (tid < RPB) cur[tid] += a;
        __syncthreads();
    }
    if (tid < RPB) {
        int excl = cur[tid] - v;
        int row = b * RPB + tid;
        if (row < NTOT) rowptr[row] = bb0 + excl;
        cur[tid] = excl;
    }
    if (b == NBUCK - 1 && tid == 0) rowptr[NTOT] = bb1;
    __syncthreads();
    for (int e = bb0 + tid; e < bb1; e += 1024) {
        int2 t = tmp[e];
        int rl = ((unsigned)t.x) >> 18;
        int p = bb0 + atomicAdd(&cur[rl], 1);
        float val = __int_as_float(t.y);
        unsigned q = (unsigned)__float2int_rn(val * 16384.f);
        if (q > 16383u) q = 16383u;
        fin[p] = (((unsigned)t.x & 0x3FFFFu) << 14) | q;
    }
}

// x0h bf16-packed: uint j of row r = comps (2j, 2j+1).
__global__ void convert_kernel(const float2* __restrict__ user, const float2* __restrict__ item,
                               unsigned* __restrict__ xh2) {
    int i = blockIdx.x * blockDim.x + threadIdx.x;   // = row*32 + j
    if (i >= NTOT * 32) return;
    float2 v = (i < NUSERS * 32) ? user[i] : item[i - NUSERS * 32];
    xh2[i] = (unsigned)benc(v.x) | ((unsigned)benc(v.y) << 16);
}

// SpMM: 8 rows/wave (8-lane octets), uint4 gathers (16B/lane), unroll 8.
// Lane (oct, s): row = wid*8+oct, comps [8s, 8s+8). 64 edges in flight per wave.
__global__ void __launch_bounds__(256)
spmm_kernel(const int* __restrict__ rowptr, const unsigned* __restrict__ ed,
            const uint4* __restrict__ xin, uint4* __restrict__ yout,
            const float4* __restrict__ user, const float4* __restrict__ item,
            const uint4* __restrict__ y1, float4* __restrict__ out, int last) {
    int wid = blockIdx.x * (blockDim.x >> 6) + (threadIdx.x >> 6);
    int lane = threadIdx.x & 63;
    int oct = lane >> 3, s = lane & 7;
    int r = wid * 8 + oct;
    if (r >= NTOT) return;
    int start = rowptr[r];
    int end   = rowptr[r + 1];
    const float SCL = 1.f / 16384.f;
    float a0 = 0.f, a1 = 0.f, a2 = 0.f, a3 = 0.f, a4 = 0.f, a5 = 0.f, a6 = 0.f, a7 = 0.f;
    int i = start;
    for (; i + 8 <= end; i += 8) {
        unsigned e[8];
#pragma unroll
        for (int u = 0; u < 8; ++u) e[u] = ed[i + u];
        uint4 g[8];
#pragma unroll
        for (int u = 0; u < 8; ++u) g[u] = xin[(size_t)(e[u] >> 14) * 8 + s];
#pragma unroll
        for (int u = 0; u < 8; ++u) {
            float v = (float)(e[u] & 0x3FFFu) * SCL;
            a0 += v * blo(g[u].x); a1 += v * bhi(g[u].x);
            a2 += v * blo(g[u].y); a3 += v * bhi(g[u].y);
            a4 += v * blo(g[u].z); a5 += v * bhi(g[u].z);
            a6 += v * blo(g[u].w); a7 += v * bhi(g[u].w);
        }
    }
    for (; i < end; ++i) {
        unsigned e = ed[i];
        uint4 g = xin[(size_t)(e >> 14) * 8 + s];
        float v = (float)(e & 0x3FFFu) * SCL;
        a0 += v * blo(g.x); a1 += v * bhi(g.x);
        a2 += v * blo(g.y); a3 += v * bhi(g.y);
        a4 += v * blo(g.z); a5 += v * bhi(g.z);
        a6 += v * blo(g.w); a7 += v * bhi(g.w);
    }
    if (!last) {
        uint4 o;
        o.x = (unsigned)benc(a0) | ((unsigned)benc(a1) << 16);
        o.y = (unsigned)benc(a2) | ((unsigned)benc(a3) << 16);
        o.z = (unsigned)benc(a4) | ((unsigned)benc(a5) << 16);
        o.w = (unsigned)benc(a6) | ((unsigned)benc(a7) << 16);
        yout[(size_t)r * 8 + s] = o;
    } else {
        size_t f4 = (size_t)r * 16 + 2 * s;   // float4 index of comps [8s, 8s+4)
        float4 x0a = (r < NUSERS) ? user[f4]     : item[f4     - (size_t)NUSERS * 16];
        float4 x0b = (r < NUSERS) ? user[f4 + 1] : item[f4 + 1 - (size_t)NUSERS * 16];
        uint4 u1 = y1[(size_t)r * 8 + s];
        uint4 u2 = xin[(size_t)r * 8 + s];   // layer-3 input IS y2
        float4 oa, ob;
        oa.x = 0.25f * (x0a.x + blo(u1.x) + blo(u2.x) + a0);
        oa.y = 0.25f * (x0a.y + bhi(u1.x) + bhi(u2.x) + a1);
        oa.z = 0.25f * (x0a.z + blo(u1.y) + blo(u2.y) + a2);
        oa.w = 0.25f * (x0a.w + bhi(u1.y) + bhi(u2.y) + a3);
        ob.x = 0.25f * (x0b.x + blo(u1.z) + blo(u2.z) + a4);
        ob.y = 0.25f * (x0b.y + bhi(u1.z) + bhi(u2.z) + a5);
        ob.z = 0.25f * (x0b.z + blo(u1.w) + blo(u2.w) + a6);
        ob.w = 0.25f * (x0b.w + bhi(u1.w) + bhi(u2.w) + a7);
        out[f4]     = oa;
        out[f4 + 1] = ob;
    }
}

extern "C" void kernel_launch(void* const* d_in, const int* in_sizes, int n_in,
                              void* d_out, int out_size, void* d_ws, size_t ws_size,
                              hipStream_t stream) {
    const float* user = (const float*)d_in[0];
    const float* item = (const float*)d_in[1];
    const float* vals = (const float*)d_in[2];
    const int*   rows = (const int*)d_in[3];
    const int*   cols = (const int*)d_in[4];
    float* out = (float*)d_out;

    // ws layout (~97 MB): tmp 38.4M | fin 19.2M | bufA 19.2M | bufB 19.2M |
    // rowptr 600K | cnt/bptr/gcur ~3.6K
    char* w = (char*)d_ws;
    int2*     tmp    = (int2*)w;     w += (size_t)NNZ_E * 8;
    unsigned* fin    = (unsigned*)w; w += (size_t)NNZ_E * 4;
    unsigned* bufA   = (unsigned*)w; w += (size_t)NTOT * DIM * 2;   // x0h, later y2h
    unsigned* bufB   = (unsigned*)w; w += (size_t)NTOT * DIM * 2;   // y1h
    int*      rowptr = (int*)w;      w += (size_t)(NTOT + 1) * 4;
    int*      cnt    = (int*)w;      w += (size_t)NBUCK * 4;
    int*      bptr   = (int*)w;      w += (size_t)(NBUCK + 1) * 4;
    int*      gcur   = (int*)w;

    const int blk = 256;
    const int gConv = (NTOT * 32 + blk - 1) / blk;       // 18750
    const int gSpmm = (NTOT / 8 + 3) / 4;                // 4688 (4 waves/block, 8 rows/wave)

    // Two-phase counting sort
    zero_int<<<2, blk, 0, stream>>>(cnt, NBUCK);
    histb_kernel<<<1024, blk, 0, stream>>>(rows, cnt);
    scanb_kernel<<<1, 512, 0, stream>>>(cnt, bptr, gcur);
    partA_kernel<<<NPART, 512, 0, stream>>>(rows, cols, vals, gcur, tmp);
    partB_kernel<<<NBUCK, 1024, 0, stream>>>(bptr, tmp, fin, rowptr);

    // Layer input in bf16
    convert_kernel<<<gConv, blk, 0, stream>>>((const float2*)user, (const float2*)item, bufA);

    // 3 propagation layers; layer 3 fuses the stage-mean into out
    spmm_kernel<<<gSpmm, blk, 0, stream>>>(rowptr, fin, (const uint4*)bufA, (uint4*)bufB,
                                           (const float4*)user, (const float4*)item,
                                           (const uint4*)bufB, (float4*)out, 0);  // y1=bufB
    spmm_kernel<<<gSpmm, blk, 0, stream>>>(rowptr, fin, (const uint4*)bufB, (uint4*)bufA,
                                           (const float4*)user, (const float4*)item,
                                           (const uint4*)bufB, (float4*)out, 0);  // y2=bufA
    spmm_kernel<<<gSpmm, blk, 0, stream>>>(rowptr, fin, (const uint4*)bufA, (uint4*)bufA,
                                           (const float4*)user, (const float4*)item,
                                           (const uint4*)bufB, (float4*)out, 1);  // fused mean
}